// Round 2
// baseline (119.398 us; speedup 1.0000x reference)
//
#include <hip/hip_runtime.h>

typedef short bf16x8 __attribute__((ext_vector_type(8)));
typedef float f32x4 __attribute__((ext_vector_type(4)));

#define B_    8
#define L_    500
#define LP    512
#define H_    16
#define DK    64
#define DM    1024
#define MP    4096
#define NTILE 16

static __device__ __forceinline__ unsigned short f2bf(float x) {
  unsigned u = __float_as_uint(x);
  u += 0x7fffu + ((u >> 16) & 1u);   // RNE
  return (unsigned short)(u >> 16);
}

static __device__ __forceinline__ void gload16(const void* g, void* l) {
  __builtin_amdgcn_global_load_lds(
      (const __attribute__((address_space(1))) void*)g,
      (__attribute__((address_space(3))) void*)l, 16, 0, 0);
}

// ---------- f32 -> bf16 for query/key/value, zero-pad rows 4000..4095 ----------
__global__ __launch_bounds__(256) void conv_x_kernel(
    const float* __restrict__ iq, const float* __restrict__ ik,
    const float* __restrict__ iv, unsigned short* __restrict__ X) {
  const int z = blockIdx.y;
  const float* src = (z == 0) ? iq : (z == 1) ? ik : iv;
  const size_t flat = (size_t)blockIdx.x * 256 + threadIdx.x;
  const size_t off = flat * 8;
  const int m = (int)(off >> 10);
  unsigned short o[8];
  if (m < 4000) {
    const float4 a = *(const float4*)(src + off);
    const float4 b = *(const float4*)(src + off + 4);
    o[0]=f2bf(a.x); o[1]=f2bf(a.y); o[2]=f2bf(a.z); o[3]=f2bf(a.w);
    o[4]=f2bf(b.x); o[5]=f2bf(b.y); o[6]=f2bf(b.z); o[7]=f2bf(b.w);
  } else {
#pragma unroll
    for (int i = 0; i < 8; ++i) o[i] = 0;
  }
  uint4 pk;
  pk.x = (unsigned)o[0] | ((unsigned)o[1] << 16);
  pk.y = (unsigned)o[2] | ((unsigned)o[3] << 16);
  pk.z = (unsigned)o[4] | ((unsigned)o[5] << 16);
  pk.w = (unsigned)o[6] | ((unsigned)o[7] << 16);
  *(uint4*)(X + (size_t)z * MP * DM + off) = pk;
}

// ---------- W (k,n) f32 -> Wt (n,k) bf16, LDS transpose (full 64x64 tile) ----------
__global__ __launch_bounds__(256) void conv_w_kernel(
    const float* __restrict__ wq, const float* __restrict__ wk,
    const float* __restrict__ wv, unsigned short* __restrict__ Wt) {
  const int z = blockIdx.y;
  const float* W = (z == 0) ? wq : (z == 1) ? wk : wv;
  const int k0 = (blockIdx.x >> 4) * 64;
  const int n0 = (blockIdx.x & 15) * 64;
  __shared__ float t[64][65];
  const int tid = threadIdx.x;
  const int row = tid >> 2;           // k within tile, 0..63
  const int cb  = (tid & 3) * 16;     // n base
#pragma unroll
  for (int s = 0; s < 4; ++s) {
    const float4 v = *(const float4*)(W + (size_t)(k0 + row) * DM + n0 + cb + s * 4);
    t[row][cb + s * 4 + 0] = v.x; t[row][cb + s * 4 + 1] = v.y;
    t[row][cb + s * 4 + 2] = v.z; t[row][cb + s * 4 + 3] = v.w;
  }
  __syncthreads();
  const int nr = tid >> 2;            // n within tile, 0..63
  const int kb = (tid & 3) * 16;      // k base
#pragma unroll
  for (int s = 0; s < 2; ++s) {
    unsigned short o[8];
#pragma unroll
    for (int e = 0; e < 8; ++e) o[e] = f2bf(t[kb + s * 8 + e][nr]);
    uint4 pk;
    pk.x = (unsigned)o[0] | ((unsigned)o[1] << 16);
    pk.y = (unsigned)o[2] | ((unsigned)o[3] << 16);
    pk.z = (unsigned)o[4] | ((unsigned)o[5] << 16);
    pk.w = (unsigned)o[6] | ((unsigned)o[7] << 16);
    *(uint4*)(Wt + (size_t)z * DM * DM + (size_t)(n0 + nr) * DM + k0 + kb + s * 8) = pk;
  }
}

// ---------- fused QKV projection GEMM (m97 structure) ----------
// C[m][n] = sum_k X[m][k]*W[k][n] + bias[n]; out -> [b][h][l(512)][64] bf16
__global__ __launch_bounds__(256) void gemm_qkv_kernel(
    const unsigned short* __restrict__ X, const unsigned short* __restrict__ Wt,
    const float* __restrict__ bq, const float* __restrict__ bk,
    const float* __restrict__ bv,
    unsigned short* __restrict__ qo, unsigned short* __restrict__ ko,
    unsigned short* __restrict__ vo) {
  const int z = blockIdx.y;
  const unsigned short* A  = X  + (size_t)z * MP * DM;
  const unsigned short* Bw = Wt + (size_t)z * DM * DM;
  const float* bias = (z == 0) ? bq : (z == 1) ? bk : bv;
  unsigned short* out = (z == 0) ? qo : (z == 1) ? ko : vo;

  const int tm = blockIdx.x >> 3, tn = blockIdx.x & 7;
  const int tid = threadIdx.x;
  const int lane = tid & 63, wid = tid >> 6;
  const int wr = wid >> 1, wc = wid & 1;
  const int lg = lane >> 4, lr = lane & 15;

  __shared__ unsigned short sA[2][128 * 32];
  __shared__ unsigned short sB[2][128 * 32];

  const int c0 = tid, c1 = tid + 256;
  const int ar0 = c0 >> 2, ak0 = (c0 & 3) * 8;
  const int ar1 = c1 >> 2, ak1 = (c1 & 3) * 8;
  const unsigned short* Ab = A  + (size_t)tm * 128 * DM;
  const unsigned short* Bb = Bw + (size_t)tn * 128 * DM;

  f32x4 acc[4][4];
#pragma unroll
  for (int i = 0; i < 4; ++i)
#pragma unroll
    for (int j = 0; j < 4; ++j) acc[i][j] = (f32x4){0.f, 0.f, 0.f, 0.f};

  gload16(Ab + (size_t)ar0 * DM + ak0, &sA[0][c0 * 8]);
  gload16(Ab + (size_t)ar1 * DM + ak1, &sA[0][c1 * 8]);
  gload16(Bb + (size_t)ar0 * DM + ak0, &sB[0][c0 * 8]);
  gload16(Bb + (size_t)ar1 * DM + ak1, &sB[0][c1 * 8]);
  asm volatile("s_waitcnt vmcnt(0)" ::: "memory");
  __syncthreads();

  int cur = 0;
  for (int t = 0; t < 32; ++t) {
    if (t < 31) {
      const int kn = (t + 1) * 32;
      gload16(Ab + (size_t)ar0 * DM + kn + ak0, &sA[cur ^ 1][c0 * 8]);
      gload16(Ab + (size_t)ar1 * DM + kn + ak1, &sA[cur ^ 1][c1 * 8]);
      gload16(Bb + (size_t)ar0 * DM + kn + ak0, &sB[cur ^ 1][c0 * 8]);
      gload16(Bb + (size_t)ar1 * DM + kn + ak1, &sB[cur ^ 1][c1 * 8]);
    }
    bf16x8 af[4], bfr[4];
#pragma unroll
    for (int s = 0; s < 4; ++s) {
      af[s]  = *(const bf16x8*)&sA[cur][(wr * 64 + s * 16 + lr) * 32 + lg * 8];
      bfr[s] = *(const bf16x8*)&sB[cur][(wc * 64 + s * 16 + lr) * 32 + lg * 8];
    }
#pragma unroll
    for (int i = 0; i < 4; ++i)
#pragma unroll
      for (int j = 0; j < 4; ++j)
        acc[i][j] = __builtin_amdgcn_mfma_f32_16x16x32_bf16(af[i], bfr[j], acc[i][j], 0, 0, 0);
    asm volatile("s_waitcnt vmcnt(0)" ::: "memory");
    __syncthreads();
    cur ^= 1;
  }

  const int nbase = tn * 128 + wc * 64 + lr;
  float bias4[4];
#pragma unroll
  for (int ns = 0; ns < 4; ++ns) bias4[ns] = bias[nbase + ns * 16];

#pragma unroll
  for (int ms = 0; ms < 4; ++ms) {
#pragma unroll
    for (int r = 0; r < 4; ++r) {
      const int m = tm * 128 + wr * 64 + ms * 16 + lg * 4 + r;
      if (m < 4000) {
        const unsigned batch = (unsigned)m / 500u;
        const int lrow = m - (int)batch * 500;
#pragma unroll
        for (int ns = 0; ns < 4; ++ns) {
          const int n = nbase + ns * 16;
          const int hh = n >> 6, d = n & 63;
          out[(((size_t)batch * H_ + hh) * LP + lrow) * DK + d] =
              f2bf(acc[ms][ns][r] + bias4[ns]);
        }
      }
    }
  }
}

// ---------- V [bh][l][d] -> Vt [bh][d][l], zero-fill l >= 500 (full 64x64 tile) ----------
__global__ __launch_bounds__(256) void transpose_v_kernel(
    const unsigned short* __restrict__ v, unsigned short* __restrict__ vt) {
  const int bh = blockIdx.y;
  const int l0 = blockIdx.x * 64;
  __shared__ unsigned short t[64][72];
  const int tid = threadIdx.x;
  const int lrw = tid >> 2, dc = (tid & 3) * 16;
  const int gl = l0 + lrw;
  if (gl < L_) {
    *(uint4*)&t[lrw][dc]     = *(const uint4*)(v + ((size_t)bh * LP + gl) * DK + dc);
    *(uint4*)&t[lrw][dc + 8] = *(const uint4*)(v + ((size_t)bh * LP + gl) * DK + dc + 8);
  } else {
    const uint4 zz = {0u, 0u, 0u, 0u};
    *(uint4*)&t[lrw][dc]     = zz;
    *(uint4*)&t[lrw][dc + 8] = zz;
  }
  __syncthreads();
  const int dr = tid >> 2, lcb = (tid & 3) * 16;
#pragma unroll
  for (int s = 0; s < 2; ++s) {
    unsigned short e[8];
#pragma unroll
    for (int i = 0; i < 8; ++i) e[i] = t[lcb + s * 8 + i][dr];
    uint4 o;
    o.x = (unsigned)e[0] | ((unsigned)e[1] << 16);
    o.y = (unsigned)e[2] | ((unsigned)e[3] << 16);
    o.z = (unsigned)e[4] | ((unsigned)e[5] << 16);
    o.w = (unsigned)e[6] | ((unsigned)e[7] << 16);
    *(uint4*)(vt + ((size_t)bh * DK + dr) * LP + l0 + lcb + s * 8) = o;
  }
}

// ---------- flash attention with relative-position bias ----------
__global__ __launch_bounds__(256) void attn_kernel(
    const unsigned short* __restrict__ q, const unsigned short* __restrict__ k,
    const unsigned short* __restrict__ vt, const float* __restrict__ rel,
    float* __restrict__ out) {
  const int bh = blockIdx.y;           // b*16 + h
  const int qc = blockIdx.x;           // 0..7, 64 q-rows each
  const int b = bh >> 4, h = bh & 15;
  const int tid = threadIdx.x;
  const int lane = tid & 63, wid = tid >> 6;
  const int lg = lane >> 4, lr = lane & 15;

  __shared__ unsigned short kt[32][72];     // K tile, padded
  __shared__ unsigned short vtt[64][40];    // V^T tile
  __shared__ unsigned short pl[4][16][40];  // per-wave P round-trip
  __shared__ float relb[576];

  const int rbase = qc * 64 - 12;
  for (int i = tid; i < 575; i += 256) {
    int idx = rbase + i;
    idx = idx < 0 ? 0 : (idx > 998 ? 998 : idx);
    relb[i] = rel[h * 999 + idx];
  }

  const int qrow = qc * 64 + wid * 16 + lr;          // A-frag row = lane&15
  const unsigned short* qp = q + ((size_t)bh * LP + qrow) * DK + lg * 8;
  const bf16x8 qf0 = *(const bf16x8*)qp;
  const bf16x8 qf1 = *(const bf16x8*)(qp + 32);

  f32x4 o[4];
#pragma unroll
  for (int d = 0; d < 4; ++d) o[d] = (f32x4){0.f, 0.f, 0.f, 0.f};
  float mrun[4], lrun[4];
#pragma unroll
  for (int r = 0; r < 4; ++r) { mrun[r] = -1e30f; lrun[r] = 0.f; }

  const int srow = tid >> 3, skc = (tid & 7) * 8;
  const int vrow = tid >> 2, svc = (tid & 3) * 8;
  const unsigned short* kbase = k  + ((size_t)bh * LP + srow) * DK + skc;
  const unsigned short* vbase = vt + ((size_t)bh * DK + vrow) * LP + svc;

  __syncthreads();

  for (int t = 0; t < NTILE; ++t) {
    const int jb = t * 32;
    *(uint4*)&kt[srow][skc]  = *(const uint4*)(kbase + (size_t)jb * DK);
    *(uint4*)&vtt[vrow][svc] = *(const uint4*)(vbase + jb);
    __syncthreads();

    f32x4 s0 = (f32x4){0.f, 0.f, 0.f, 0.f};
    f32x4 s1 = (f32x4){0.f, 0.f, 0.f, 0.f};
    {
      const bf16x8 k00 = *(const bf16x8*)&kt[lr][lg * 8];
      const bf16x8 k01 = *(const bf16x8*)&kt[lr][lg * 8 + 32];
      const bf16x8 k10 = *(const bf16x8*)&kt[16 + lr][lg * 8];
      const bf16x8 k11 = *(const bf16x8*)&kt[16 + lr][lg * 8 + 32];
      s0 = __builtin_amdgcn_mfma_f32_16x16x32_bf16(qf0, k00, s0, 0, 0, 0);
      s0 = __builtin_amdgcn_mfma_f32_16x16x32_bf16(qf1, k01, s0, 0, 0, 0);
      s1 = __builtin_amdgcn_mfma_f32_16x16x32_bf16(qf0, k10, s1, 0, 0, 0);
      s1 = __builtin_amdgcn_mfma_f32_16x16x32_bf16(qf1, k11, s1, 0, 0, 0);
    }

    float sc0[4], sc1[4];
    const int irow0 = wid * 16 + lg * 4;
#pragma unroll
    for (int r = 0; r < 4; ++r) {
      const int j0 = jb + lr, j1 = jb + 16 + lr;
      float v0 = s0[r] * 0.125f + relb[irow0 + r - j0 + 511];
      float v1 = s1[r] * 0.125f + relb[irow0 + r - j1 + 511];
      if (j0 >= 500) v0 = -1e30f;
      if (j1 >= 500) v1 = -1e30f;
      sc0[r] = v0; sc1[r] = v1;
    }

    float mx[4], alpha[4], rs[4];
#pragma unroll
    for (int r = 0; r < 4; ++r) mx[r] = fmaxf(sc0[r], sc1[r]);
#pragma unroll
    for (int d = 1; d < 16; d <<= 1)
#pragma unroll
      for (int r = 0; r < 4; ++r) mx[r] = fmaxf(mx[r], __shfl_xor(mx[r], d));
#pragma unroll
    for (int r = 0; r < 4; ++r) {
      const float mn = fmaxf(mrun[r], mx[r]);
      alpha[r] = __expf(mrun[r] - mn);
      mrun[r] = mn;
      sc0[r] = __expf(sc0[r] - mn);
      sc1[r] = __expf(sc1[r] - mn);
      rs[r] = sc0[r] + sc1[r];
    }
#pragma unroll
    for (int d = 1; d < 16; d <<= 1)
#pragma unroll
      for (int r = 0; r < 4; ++r) rs[r] += __shfl_xor(rs[r], d);
#pragma unroll
    for (int r = 0; r < 4; ++r) lrun[r] = lrun[r] * alpha[r] + rs[r];
#pragma unroll
    for (int d = 0; d < 4; ++d) {
      o[d][0] *= alpha[0]; o[d][1] *= alpha[1];
      o[d][2] *= alpha[2]; o[d][3] *= alpha[3];
    }

#pragma unroll
    for (int r = 0; r < 4; ++r) {
      pl[wid][lg * 4 + r][lr]      = f2bf(sc0[r]);
      pl[wid][lg * 4 + r][16 + lr] = f2bf(sc1[r]);
    }

    const bf16x8 pf = *(const bf16x8*)&pl[wid][lr][lg * 8];
#pragma unroll
    for (int d = 0; d < 4; ++d) {
      const bf16x8 vf = *(const bf16x8*)&vtt[d * 16 + lr][lg * 8];
      o[d] = __builtin_amdgcn_mfma_f32_16x16x32_bf16(pf, vf, o[d], 0, 0, 0);
    }
    __syncthreads();
  }

#pragma unroll
  for (int r = 0; r < 4; ++r) {
    const int i = qc * 64 + wid * 16 + lg * 4 + r;
    if (i < 500) {
      const float inv = 1.0f / lrun[r];
      float* op = out + ((size_t)b * L_ + i) * DM + h * DK + lr;
#pragma unroll
      for (int d = 0; d < 4; ++d) op[d * 16] = o[d][r] * inv;
    }
  }
}

extern "C" void kernel_launch(void* const* d_in, const int* in_sizes, int n_in,
                              void* d_out, int out_size, void* d_ws, size_t ws_size,
                              hipStream_t stream) {
  const float* iq  = (const float*)d_in[0];
  const float* ik  = (const float*)d_in[1];
  const float* iv  = (const float*)d_in[2];
  const float* wq  = (const float*)d_in[3];
  const float* bq  = (const float*)d_in[4];
  const float* wk  = (const float*)d_in[5];
  const float* bk  = (const float*)d_in[6];
  const float* wv  = (const float*)d_in[7];
  const float* bv  = (const float*)d_in[8];
  const float* rel = (const float*)d_in[9];
  float* out = (float*)d_out;

  char* w = (char*)d_ws;
  unsigned short* X   = (unsigned short*)(w);                 // [3][4096][1024] bf16
  unsigned short* Wt  = (unsigned short*)(w + 25165824);      // [3][1024][1024] bf16 (n,k)
  unsigned short* qb  = (unsigned short*)(w + 31457280);      // [128][512][64] bf16
  unsigned short* kb  = (unsigned short*)(w + 39845888);
  unsigned short* vb  = (unsigned short*)(w + 48234496);
  unsigned short* vtb = (unsigned short*)(w);                 // [128][64][512], overlaps X (dead)

  conv_x_kernel<<<dim3(2048, 3), 256, 0, stream>>>(iq, ik, iv, X);
  conv_w_kernel<<<dim3(256, 3), 256, 0, stream>>>(wq, wk, wv, Wt);
  gemm_qkv_kernel<<<dim3(256, 3), 256, 0, stream>>>(X, Wt, bq, bk, bv, qb, kb, vb);
  transpose_v_kernel<<<dim3(8, 128), 256, 0, stream>>>(vb, vtb);
  attn_kernel<<<dim3(8, 128), 256, 0, stream>>>(qb, kb, vtb, rel, out);
}

// Round 3
// 99.836 us; speedup vs baseline: 1.1959x; 1.1959x over previous
//
#include <hip/hip_runtime.h>

typedef short bf16x8 __attribute__((ext_vector_type(8)));
typedef float f32x4 __attribute__((ext_vector_type(4)));

#define B_    8
#define L_    500
#define LP    512
#define H_    16
#define DK    64
#define DM    1024
#define MP    4096
#define NT    8      // 512 / 64 keys per tile

static __device__ __forceinline__ unsigned short f2bf(float x) {
  unsigned u = __float_as_uint(x);
  u += 0x7fffu + ((u >> 16) & 1u);   // RNE
  return (unsigned short)(u >> 16);
}

static __device__ __forceinline__ void gload16(const void* g, void* l) {
  __builtin_amdgcn_global_load_lds(
      (const __attribute__((address_space(1))) void*)g,
      (__attribute__((address_space(3))) void*)l, 16, 0, 0);
}

// ---------- f32 -> bf16 for query/key/value, zero-pad rows 4000..4095 ----------
__global__ __launch_bounds__(256) void conv_x_kernel(
    const float* __restrict__ iq, const float* __restrict__ ik,
    const float* __restrict__ iv, unsigned short* __restrict__ X) {
  const int z = blockIdx.y;
  const float* src = (z == 0) ? iq : (z == 1) ? ik : iv;
  const size_t flat = (size_t)blockIdx.x * 256 + threadIdx.x;
  const size_t off = flat * 8;
  const int m = (int)(off >> 10);
  unsigned short o[8];
  if (m < 4000) {
    const float4 a = *(const float4*)(src + off);
    const float4 b = *(const float4*)(src + off + 4);
    o[0]=f2bf(a.x); o[1]=f2bf(a.y); o[2]=f2bf(a.z); o[3]=f2bf(a.w);
    o[4]=f2bf(b.x); o[5]=f2bf(b.y); o[6]=f2bf(b.z); o[7]=f2bf(b.w);
  } else {
#pragma unroll
    for (int i = 0; i < 8; ++i) o[i] = 0;
  }
  uint4 pk;
  pk.x = (unsigned)o[0] | ((unsigned)o[1] << 16);
  pk.y = (unsigned)o[2] | ((unsigned)o[3] << 16);
  pk.z = (unsigned)o[4] | ((unsigned)o[5] << 16);
  pk.w = (unsigned)o[6] | ((unsigned)o[7] << 16);
  *(uint4*)(X + (size_t)z * MP * DM + off) = pk;
}

// ---------- W (k,n) f32 -> Wt (n,k) bf16, LDS transpose (full 64x64 tile) ----------
__global__ __launch_bounds__(256) void conv_w_kernel(
    const float* __restrict__ wq, const float* __restrict__ wk,
    const float* __restrict__ wv, unsigned short* __restrict__ Wt) {
  const int z = blockIdx.y;
  const float* W = (z == 0) ? wq : (z == 1) ? wk : wv;
  const int k0 = (blockIdx.x >> 4) * 64;
  const int n0 = (blockIdx.x & 15) * 64;
  __shared__ float t[64][65];
  const int tid = threadIdx.x;
  const int row = tid >> 2;
  const int cb  = (tid & 3) * 16;
#pragma unroll
  for (int s = 0; s < 4; ++s) {
    const float4 v = *(const float4*)(W + (size_t)(k0 + row) * DM + n0 + cb + s * 4);
    t[row][cb + s * 4 + 0] = v.x; t[row][cb + s * 4 + 1] = v.y;
    t[row][cb + s * 4 + 2] = v.z; t[row][cb + s * 4 + 3] = v.w;
  }
  __syncthreads();
  const int nr = tid >> 2;
  const int kb = (tid & 3) * 16;
#pragma unroll
  for (int s = 0; s < 2; ++s) {
    unsigned short o[8];
#pragma unroll
    for (int e = 0; e < 8; ++e) o[e] = f2bf(t[kb + s * 8 + e][nr]);
    uint4 pk;
    pk.x = (unsigned)o[0] | ((unsigned)o[1] << 16);
    pk.y = (unsigned)o[2] | ((unsigned)o[3] << 16);
    pk.z = (unsigned)o[4] | ((unsigned)o[5] << 16);
    pk.w = (unsigned)o[6] | ((unsigned)o[7] << 16);
    *(uint4*)(Wt + (size_t)z * DM * DM + (size_t)(n0 + nr) * DM + k0 + kb + s * 8) = pk;
  }
}

// ---------- fused QKV projection GEMM (m97 structure, XCD-swizzled) ----------
__global__ __launch_bounds__(256) void gemm_qkv_kernel(
    const unsigned short* __restrict__ X, const unsigned short* __restrict__ Wt,
    const float* __restrict__ bq, const float* __restrict__ bk,
    const float* __restrict__ bv,
    unsigned short* __restrict__ qo, unsigned short* __restrict__ ko,
    unsigned short* __restrict__ vo) {
  const int z = blockIdx.y;
  const unsigned short* A  = X  + (size_t)z * MP * DM;
  const unsigned short* Bw = Wt + (size_t)z * DM * DM;
  const float* bias = (z == 0) ? bq : (z == 1) ? bk : bv;
  unsigned short* out = (z == 0) ? qo : (z == 1) ? ko : vo;

  // XCD swizzle: XCD = bid%8 -> tm group; each XCD sees 4 A-panels + all B (3MB, L2-fit)
  const int bid = blockIdx.x;
  const int xg = bid & 7, y = bid >> 3;        // y in 0..31
  const int tm = xg + 8 * (y >> 3);            // 0..31
  const int tn = y & 7;                        // 0..7
  const int tid = threadIdx.x;
  const int lane = tid & 63, wid = tid >> 6;
  const int wr = wid >> 1, wc = wid & 1;
  const int lg = lane >> 4, lr = lane & 15;

  __shared__ unsigned short sA[2][128 * 32];
  __shared__ unsigned short sB[2][128 * 32];

  const int c0 = tid, c1 = tid + 256;
  const int ar0 = c0 >> 2, ak0 = (c0 & 3) * 8;
  const int ar1 = c1 >> 2, ak1 = (c1 & 3) * 8;
  const unsigned short* Ab = A  + (size_t)tm * 128 * DM;
  const unsigned short* Bb = Bw + (size_t)tn * 128 * DM;

  f32x4 acc[4][4];
#pragma unroll
  for (int i = 0; i < 4; ++i)
#pragma unroll
    for (int j = 0; j < 4; ++j) acc[i][j] = (f32x4){0.f, 0.f, 0.f, 0.f};

  gload16(Ab + (size_t)ar0 * DM + ak0, &sA[0][c0 * 8]);
  gload16(Ab + (size_t)ar1 * DM + ak1, &sA[0][c1 * 8]);
  gload16(Bb + (size_t)ar0 * DM + ak0, &sB[0][c0 * 8]);
  gload16(Bb + (size_t)ar1 * DM + ak1, &sB[0][c1 * 8]);
  asm volatile("s_waitcnt vmcnt(0)" ::: "memory");
  __syncthreads();

  int cur = 0;
  for (int t = 0; t < 32; ++t) {
    if (t < 31) {
      const int kn = (t + 1) * 32;
      gload16(Ab + (size_t)ar0 * DM + kn + ak0, &sA[cur ^ 1][c0 * 8]);
      gload16(Ab + (size_t)ar1 * DM + kn + ak1, &sA[cur ^ 1][c1 * 8]);
      gload16(Bb + (size_t)ar0 * DM + kn + ak0, &sB[cur ^ 1][c0 * 8]);
      gload16(Bb + (size_t)ar1 * DM + kn + ak1, &sB[cur ^ 1][c1 * 8]);
    }
    bf16x8 af[4], bfr[4];
#pragma unroll
    for (int s = 0; s < 4; ++s) {
      af[s]  = *(const bf16x8*)&sA[cur][(wr * 64 + s * 16 + lr) * 32 + lg * 8];
      bfr[s] = *(const bf16x8*)&sB[cur][(wc * 64 + s * 16 + lr) * 32 + lg * 8];
    }
#pragma unroll
    for (int i = 0; i < 4; ++i)
#pragma unroll
      for (int j = 0; j < 4; ++j)
        acc[i][j] = __builtin_amdgcn_mfma_f32_16x16x32_bf16(af[i], bfr[j], acc[i][j], 0, 0, 0);
    asm volatile("s_waitcnt vmcnt(0)" ::: "memory");
    __syncthreads();
    cur ^= 1;
  }

  const int nbase = tn * 128 + wc * 64 + lr;
  float bias4[4];
#pragma unroll
  for (int ns = 0; ns < 4; ++ns) bias4[ns] = bias[nbase + ns * 16];

#pragma unroll
  for (int ms = 0; ms < 4; ++ms) {
#pragma unroll
    for (int r = 0; r < 4; ++r) {
      const int m = tm * 128 + wr * 64 + ms * 16 + lg * 4 + r;
      if (m < 4000) {
        const unsigned batch = (unsigned)m / 500u;
        const int lrow = m - (int)batch * 500;
#pragma unroll
        for (int ns = 0; ns < 4; ++ns) {
          const int n = nbase + ns * 16;
          const int hh = n >> 6, d = n & 63;
          out[(((size_t)batch * H_ + hh) * LP + lrow) * DK + d] =
              f2bf(acc[ms][ns][r] + bias4[ns]);
        }
      }
    }
  }
}

// ---------- V [bh][l][d] -> Vt [bh][d][l], zero-fill l >= 500 ----------
__global__ __launch_bounds__(256) void transpose_v_kernel(
    const unsigned short* __restrict__ v, unsigned short* __restrict__ vt) {
  const int bh = blockIdx.y;
  const int l0 = blockIdx.x * 64;
  __shared__ unsigned short t[64][72];
  const int tid = threadIdx.x;
  const int lrw = tid >> 2, dc = (tid & 3) * 16;
  const int gl = l0 + lrw;
  if (gl < L_) {
    *(uint4*)&t[lrw][dc]     = *(const uint4*)(v + ((size_t)bh * LP + gl) * DK + dc);
    *(uint4*)&t[lrw][dc + 8] = *(const uint4*)(v + ((size_t)bh * LP + gl) * DK + dc + 8);
  } else {
    const uint4 zz = {0u, 0u, 0u, 0u};
    *(uint4*)&t[lrw][dc]     = zz;
    *(uint4*)&t[lrw][dc + 8] = zz;
  }
  __syncthreads();
  const int dr = tid >> 2, lcb = (tid & 3) * 16;
#pragma unroll
  for (int s = 0; s < 2; ++s) {
    unsigned short e[8];
#pragma unroll
    for (int i = 0; i < 8; ++i) e[i] = t[lcb + s * 8 + i][dr];
    uint4 o;
    o.x = (unsigned)e[0] | ((unsigned)e[1] << 16);
    o.y = (unsigned)e[2] | ((unsigned)e[3] << 16);
    o.z = (unsigned)e[4] | ((unsigned)e[5] << 16);
    o.w = (unsigned)e[6] | ((unsigned)e[7] << 16);
    *(uint4*)(vt + ((size_t)bh * DK + dr) * LP + l0 + lcb + s * 8) = o;
  }
}

// ---------- flash attention: 64-key tiles, dbuf LDS, slab layouts, defer-max ----------
__global__ __launch_bounds__(256) void attn_kernel(
    const unsigned short* __restrict__ q, const unsigned short* __restrict__ k,
    const unsigned short* __restrict__ vt, const float* __restrict__ rel,
    float* __restrict__ out) {
  const int id = blockIdx.x;           // XCD = id%8 = bh%8 -> per-XCD K/V locality
  const int bh = id & 127, qc = id >> 7;
  const int b = bh >> 4, h = bh & 15;
  const int tid = threadIdx.x;
  const int lane = tid & 63, wid = tid >> 6;
  const int lg = lane >> 4, lr = lane & 15;

  // slab layouts: each [16][32] slab = 1KB contiguous -> conflict-free b128
  __shared__ unsigned short kt[2][8][16][32];   // [buf][(key>>4)*2+dhalf][key&15][d&31]
  __shared__ unsigned short vtt[2][8][16][32];  // [buf][(key>>5)*4+dblk][d&15][key&31]
  __shared__ unsigned short pl[4][2][16][32];   // [wid][key>>5][qrow][key&31]
  __shared__ float relb[576];

  const float LOG2E = 1.44269504f;
  const float SC = 0.125f * LOG2E;
  const int rbase = qc * 64 - 12;
  for (int i = tid; i < 575; i += 256) {
    int idx = rbase + i;
    idx = idx < 0 ? 0 : (idx > 998 ? 998 : idx);
    relb[i] = rel[h * 999 + idx] * LOG2E;
  }

  const int qrow = qc * 64 + wid * 16 + lr;
  const unsigned short* qp = q + ((size_t)bh * LP + qrow) * DK + lg * 8;
  const bf16x8 qf0 = *(const bf16x8*)qp;
  const bf16x8 qf1 = *(const bf16x8*)(qp + 32);

  // staging: K thread -> key kj, d-range kdg (16 wide, 2x uint4)
  const int kj = tid >> 2, kdg = (tid & 3) * 16;
  const unsigned short* kgp = k + ((size_t)bh * LP + kj) * DK + kdg;
  unsigned short* kd0 = &kt[0][(kj >> 4) * 2 + (kdg >= 32 ? 1 : 0)][kj & 15][kdg & 31];
  // V: thread -> d vd, key-range vkg
  const int vd = tid >> 2, vkg = (tid & 3) * 16;
  const unsigned short* vgp = vt + ((size_t)bh * DK + vd) * LP + vkg;
  unsigned short* vd0 = &vtt[0][(vkg >> 5) * 4 + (vd >> 4)][vd & 15][vkg & 31];

  f32x4 o[4];
#pragma unroll
  for (int d = 0; d < 4; ++d) o[d] = (f32x4){0.f, 0.f, 0.f, 0.f};
  float mrun[4], lrun[4];
#pragma unroll
  for (int r = 0; r < 4; ++r) { mrun[r] = -1e30f; lrun[r] = 0.f; }

  uint4 ka0 = *(const uint4*)(kgp);
  uint4 ka1 = *(const uint4*)(kgp + 8);
  uint4 va0 = *(const uint4*)(vgp);
  uint4 va1 = *(const uint4*)(vgp + 8);

  const int i0 = wid * 16 + lg * 4;

  for (int t = 0; t < NT; ++t) {
    const int buf = t & 1;
    *(uint4*)(kd0 + buf * 4096)     = ka0;
    *(uint4*)(kd0 + buf * 4096 + 8) = ka1;
    *(uint4*)(vd0 + buf * 4096)     = va0;
    *(uint4*)(vd0 + buf * 4096 + 8) = va1;
    __syncthreads();

    if (t < NT - 1) {   // prefetch next tile into regs; latency hides under MFMA
      const size_t ko_ = (size_t)(t + 1) * 64 * DK;
      ka0 = *(const uint4*)(kgp + ko_);
      ka1 = *(const uint4*)(kgp + ko_ + 8);
      va0 = *(const uint4*)(vgp + (t + 1) * 64);
      va1 = *(const uint4*)(vgp + (t + 1) * 64 + 8);
    }

    // QK^T: 4 key-blocks of 16
    f32x4 s[4];
#pragma unroll
    for (int c = 0; c < 4; ++c) {
      const bf16x8 b0 = *(const bf16x8*)&kt[buf][c * 2 + 0][lr][lg * 8];
      const bf16x8 b1 = *(const bf16x8*)&kt[buf][c * 2 + 1][lr][lg * 8];
      s[c] = (f32x4){0.f, 0.f, 0.f, 0.f};
      s[c] = __builtin_amdgcn_mfma_f32_16x16x32_bf16(qf0, b0, s[c], 0, 0, 0);
      s[c] = __builtin_amdgcn_mfma_f32_16x16x32_bf16(qf1, b1, s[c], 0, 0, 0);
    }

    float sc[4][4];
#pragma unroll
    for (int c = 0; c < 4; ++c) {
      const int bidx = i0 - t * 64 - c * 16 - lr + 511;
#pragma unroll
      for (int r = 0; r < 4; ++r)
        sc[c][r] = s[c][r] * SC + relb[bidx + r];
    }
    if (t == NT - 1) {
#pragma unroll
      for (int c = 0; c < 4; ++c) {
        const int j = 448 + c * 16 + lr;
        if (j >= L_) { sc[c][0] = sc[c][1] = sc[c][2] = sc[c][3] = -1e30f; }
      }
    }

    // local max + defer-max check (log2 domain, thr 11.5 -> P <= 2^11.5)
    float mloc[4];
#pragma unroll
    for (int r = 0; r < 4; ++r)
      mloc[r] = fmaxf(fmaxf(sc[0][r], sc[1][r]), fmaxf(sc[2][r], sc[3][r]));
    float dmax = fmaxf(fmaxf(mloc[0] - mrun[0], mloc[1] - mrun[1]),
                       fmaxf(mloc[2] - mrun[2], mloc[3] - mrun[3]));
    if (!__all(dmax <= 11.5f)) {
      float mx[4];
#pragma unroll
      for (int r = 0; r < 4; ++r) mx[r] = fmaxf(mloc[r], mrun[r]);
#pragma unroll
      for (int d = 1; d < 16; d <<= 1)
#pragma unroll
        for (int r = 0; r < 4; ++r) mx[r] = fmaxf(mx[r], __shfl_xor(mx[r], d));
#pragma unroll
      for (int r = 0; r < 4; ++r) {
        const float alpha = exp2f(mrun[r] - mx[r]);
        mrun[r] = mx[r];
        lrun[r] *= alpha;
        o[0][r] *= alpha; o[1][r] *= alpha; o[2][r] *= alpha; o[3][r] *= alpha;
      }
    }

    // P = exp2(sc - mrun), write to per-wave P slabs
    float rs[4] = {0.f, 0.f, 0.f, 0.f};
#pragma unroll
    for (int c = 0; c < 4; ++c) {
#pragma unroll
      for (int r = 0; r < 4; ++r) {
        const float p = exp2f(sc[c][r] - mrun[r]);
        rs[r] += p;
        pl[wid][c >> 1][lg * 4 + r][(c & 1) * 16 + lr] = f2bf(p);
      }
    }
#pragma unroll
    for (int d = 1; d < 16; d <<= 1)
#pragma unroll
      for (int r = 0; r < 4; ++r) rs[r] += __shfl_xor(rs[r], d);
#pragma unroll
    for (int r = 0; r < 4; ++r) lrun[r] += rs[r];

    // PV
#pragma unroll
    for (int kc = 0; kc < 2; ++kc) {
      const bf16x8 pf = *(const bf16x8*)&pl[wid][kc][lr][lg * 8];
#pragma unroll
      for (int db = 0; db < 4; ++db) {
        const bf16x8 vf = *(const bf16x8*)&vtt[buf][kc * 4 + db][lr][lg * 8];
        o[db] = __builtin_amdgcn_mfma_f32_16x16x32_bf16(pf, vf, o[db], 0, 0, 0);
      }
    }
  }

#pragma unroll
  for (int r = 0; r < 4; ++r) {
    const int i = qc * 64 + wid * 16 + lg * 4 + r;
    if (i < L_) {
      const float inv = 1.0f / lrun[r];
      float* op = out + ((size_t)b * L_ + i) * DM + h * DK + lr;
#pragma unroll
      for (int d = 0; d < 4; ++d) op[d * 16] = o[d][r] * inv;
    }
  }
}

extern "C" void kernel_launch(void* const* d_in, const int* in_sizes, int n_in,
                              void* d_out, int out_size, void* d_ws, size_t ws_size,
                              hipStream_t stream) {
  const float* iq  = (const float*)d_in[0];
  const float* ik  = (const float*)d_in[1];
  const float* iv  = (const float*)d_in[2];
  const float* wq  = (const float*)d_in[3];
  const float* bq  = (const float*)d_in[4];
  const float* wk  = (const float*)d_in[5];
  const float* bk  = (const float*)d_in[6];
  const float* wv  = (const float*)d_in[7];
  const float* bv  = (const float*)d_in[8];
  const float* rel = (const float*)d_in[9];
  float* out = (float*)d_out;

  char* w = (char*)d_ws;
  unsigned short* X   = (unsigned short*)(w);                 // [3][4096][1024] bf16
  unsigned short* Wt  = (unsigned short*)(w + 25165824);      // [3][1024][1024] bf16 (n,k)
  unsigned short* qb  = (unsigned short*)(w + 31457280);      // [128][512][64] bf16
  unsigned short* kb  = (unsigned short*)(w + 39845888);
  unsigned short* vb  = (unsigned short*)(w + 48234496);
  unsigned short* vtb = (unsigned short*)(w);                 // [128][64][512], overlaps X (dead)

  conv_x_kernel<<<dim3(2048, 3), 256, 0, stream>>>(iq, ik, iv, X);
  conv_w_kernel<<<dim3(256, 3), 256, 0, stream>>>(wq, wk, wv, Wt);
  gemm_qkv_kernel<<<dim3(256, 3), 256, 0, stream>>>(X, Wt, bq, bk, bv, qb, kb, vb);
  transpose_v_kernel<<<dim3(8, 128), 256, 0, stream>>>(vb, vtb);
  attn_kernel<<<1024, 256, 0, stream>>>(qb, kb, vtb, rel, out);
}